// Round 4
// baseline (430.384 us; speedup 1.0000x reference)
//
#include <hip/hip_runtime.h>

#define NTAG 64
#define SOS_T 61
#define EOS_T 62
#define BB 512
#define SS 1024
#define LOG2E 1.4426950408889634f
#define LN2   0.6931471805599453f

typedef float v2f __attribute__((ext_vector_type(2)));

// fmax with a DPP-shuffled copy of x (VALU-only cross-lane, no DS pipe).
template<int CTRL>
__device__ __forceinline__ float dppfmax(float x) {
    int xi = __float_as_int(x);
    int yi = __builtin_amdgcn_update_dpp(xi, xi, CTRL, 0xf, 0xf, false);
    return fmaxf(x, __int_as_float(yi));
}

// One wave per batch row; lane = tag. Exp-space forward recursion:
//   A_new[j] = ef[t,j] * sum_i A[i] * expT[i][j]
// Broadcast of A across lanes via 64 ds_bpermute_b32 (uniform index =
// broadcast, no LDS storage, no write->read ordering). Dot via 32
// v_pk_fma_f32. Normalization: delay-1 deadbeat feedback — a DPP fmax
// tree (off the critical chain) extracts exponent e of max(A_t); step
// t+1 multiplies by 2^-e (folded into EF before qq is ready); exact
// pow2 bookkeeping accumulates in Mf.
#define STEP(EF, MK) do {                                                    \
    int Ai_ = __float_as_int(A);                                             \
    v2f q0_ = {0.f, 0.f}, q1_ = q0_, q2_ = q0_, q3_ = q0_;                   \
    _Pragma("unroll")                                                        \
    for (int s_ = 0; s_ < 32; ++s_) {                                        \
        int bl_ = __builtin_amdgcn_ds_bpermute(8 * s_,     Ai_);             \
        int bh_ = __builtin_amdgcn_ds_bpermute(8 * s_ + 4, Ai_);             \
        v2f av_;                                                             \
        av_.x = __int_as_float(bl_);                                         \
        av_.y = __int_as_float(bh_);                                         \
        switch (s_ & 3) {                                                    \
            case 0: asm("v_pk_fma_f32 %0, %1, %2, %0" : "+v"(q0_) : "v"(av_), "v"(eT2[s_])); break; \
            case 1: asm("v_pk_fma_f32 %0, %1, %2, %0" : "+v"(q1_) : "v"(av_), "v"(eT2[s_])); break; \
            case 2: asm("v_pk_fma_f32 %0, %1, %2, %0" : "+v"(q2_) : "v"(av_), "v"(eT2[s_])); break; \
            default: asm("v_pk_fma_f32 %0, %1, %2, %0" : "+v"(q3_) : "v"(av_), "v"(eT2[s_])); break; \
        }                                                                    \
    }                                                                        \
    v2f qs_ = (q0_ + q1_) + (q2_ + q3_);                                     \
    float qq_ = qs_.x + qs_.y;                                               \
    float An_ = qq_ * ((EF) * sc1);                                          \
    A = ((MK) != 0.f) ? An_ : A;                                             \
    Mf = fmaf((MK), e1, Mf);                                                 \
    float mx_ = dppfmax<0xB1>(A);      /* xor1  (quad_perm 1,0,3,2) */       \
    mx_ = dppfmax<0x4E>(mx_);          /* xor2  (quad_perm 2,3,0,1) */       \
    mx_ = dppfmax<0x141>(mx_);         /* row_half_mirror -> 8-max  */       \
    mx_ = dppfmax<0x140>(mx_);         /* row_mirror      -> 16-max */       \
    mx_ = dppfmax<0x142>(mx_);         /* row_bcast15               */       \
    mx_ = dppfmax<0x143>(mx_);         /* row_bcast31 -> lane63 = global */  \
    int me_ = (__builtin_amdgcn_readlane(__float_as_int(mx_), 63) >> 23) - 127; \
    sc1 = __int_as_float((127 - me_) << 23);                                 \
    e1  = (float)me_;                                                        \
} while (0)

__global__ __launch_bounds__(64) void crf_nll_kernel(
    const float* __restrict__ emissions,  // [B,S,64]
    const int*   __restrict__ tags,       // [B,S]
    const float* __restrict__ mask,       // [B,S]
    const float* __restrict__ trans,      // [64,64]
    float* __restrict__ out)              // [1]
{
    const int b = blockIdx.x;
    const int j = threadIdx.x;            // tag index = lane

    __shared__ __align__(16) float T_lds[NTAG * NTAG];
    __shared__ __align__(16) float mask_lds[SS];

    // ---- stage transitions: raw copy to LDS (score lookups), exp(T) col j pairs in regs ----
    const float4* tg4 = (const float4*)trans;
    float4* tl4 = (float4*)T_lds;
#pragma unroll
    for (int i = 0; i < 16; ++i) tl4[i * 64 + j] = tg4[i * 64 + j];

    v2f eT2[32];
#pragma unroll
    for (int i = 0; i < 32; ++i) {
        eT2[i].x = exp2f(trans[(2 * i + 0) * NTAG + j] * LOG2E);  // -1e6 -> exactly 0
        eT2[i].y = exp2f(trans[(2 * i + 1) * NTAG + j] * LOG2E);
    }
    __syncthreads();   // once, prologue only

    const float* emb_g = emissions + (size_t)b * SS * NTAG;
    const int*   tgb   = tags + (size_t)b * SS;
    const float* mkb   = mask + (size_t)b * SS;

    // ---- gold-path score + msum + mask->LDS, lane-parallel over time ----
    float sc = 0.f, ms = 0.f;
#pragma unroll 4
    for (int k = 0; k < SS / 64; ++k) {
        int t = k * 64 + j;
        int tg = tgb[t];
        float m = mkb[t];
        mask_lds[t] = m;
        ms += m;
        float e = emb_g[t * NTAG + tg];
        if (t == 0) {
            sc += T_lds[SOS_T * NTAG + tg] + e;
        } else {
            int tgp = tgb[t - 1];
            sc += m * (e + T_lds[tgp * NTAG + tg]);
        }
    }
#pragma unroll
    for (int o = 32; o > 0; o >>= 1) {
        sc += __shfl_xor(sc, o);
        ms += __shfl_xor(ms, o);
    }
    int last_idx = (int)(ms + 0.5f) - 1;
    int last_tag = tgb[last_idx];
    sc += T_lds[last_tag * NTAG + EOS_T];

    // ---- t=0 init ----
    float A = exp2f((T_lds[SOS_T * NTAG + j] + emb_g[j]) * LOG2E);
    float Mf = 0.f;          // accumulated pow2 exponent (exact integer floats)
    float sc1 = 1.0f;        // pending normalization scale (2^-e of A_{t-1})
    float e1  = 0.0f;        // its exponent

    // ---- em prefetch ring, depth 16 ----
    float er[16];
#pragma unroll
    for (int k = 0; k < 16; ++k) er[k] = emb_g[(1 + k) * NTAG + j];

    // ---- main recursion: 63 groups of 16 (t = 1..1008), then 15-step tail ----
#pragma unroll 1
    for (int tb = 1; tb <= SS - 31; tb += 16) {
        float ef[16];
#pragma unroll
        for (int k = 0; k < 16; ++k) ef[k] = exp2f(er[k] * LOG2E);
#pragma unroll
        for (int k = 0; k < 16; ++k) {
            int tn = tb + 16 + k;
            tn = (tn > SS - 1) ? (SS - 1) : tn;
            er[k] = emb_g[tn * NTAG + j];
        }
        float mk[16];
#pragma unroll
        for (int k = 0; k < 16; ++k) mk[k] = mask_lds[tb + k];

        STEP(ef[0],  mk[0]);
        STEP(ef[1],  mk[1]);
        STEP(ef[2],  mk[2]);
        STEP(ef[3],  mk[3]);
        STEP(ef[4],  mk[4]);
        STEP(ef[5],  mk[5]);
        STEP(ef[6],  mk[6]);
        STEP(ef[7],  mk[7]);
        STEP(ef[8],  mk[8]);
        STEP(ef[9],  mk[9]);
        STEP(ef[10], mk[10]);
        STEP(ef[11], mk[11]);
        STEP(ef[12], mk[12]);
        STEP(ef[13], mk[13]);
        STEP(ef[14], mk[14]);
        STEP(ef[15], mk[15]);
    }
    {   // tail: t = 1009..1023 (15 steps, ring holds them)
        float ef[15];
#pragma unroll
        for (int k = 0; k < 15; ++k) ef[k] = exp2f(er[k] * LOG2E);
        float mk[15];
#pragma unroll
        for (int k = 0; k < 15; ++k) mk[k] = mask_lds[SS - 15 + k];

        STEP(ef[0],  mk[0]);
        STEP(ef[1],  mk[1]);
        STEP(ef[2],  mk[2]);
        STEP(ef[3],  mk[3]);
        STEP(ef[4],  mk[4]);
        STEP(ef[5],  mk[5]);
        STEP(ef[6],  mk[6]);
        STEP(ef[7],  mk[7]);
        STEP(ef[8],  mk[8]);
        STEP(ef[9],  mk[9]);
        STEP(ef[10], mk[10]);
        STEP(ef[11], mk[11]);
        STEP(ef[12], mk[12]);
        STEP(ef[13], mk[13]);
        STEP(ef[14], mk[14]);
    }

    // ---- finalize: log_z = ( log2( sum_j A[j]*exp(T[j][EOS]) ) + Mf ) * ln2 ----
    float val = A * exp2f(T_lds[j * NTAG + EOS_T] * LOG2E);
#pragma unroll
    for (int o = 32; o > 0; o >>= 1) val += __shfl_xor(val, o);
    float log_z = (log2f(val) + Mf) * LN2;

    if (j == 0) atomicAdd(out, log_z - sc);
}

extern "C" void kernel_launch(void* const* d_in, const int* in_sizes, int n_in,
                              void* d_out, int out_size, void* d_ws, size_t ws_size,
                              hipStream_t stream) {
    const float* emissions = (const float*)d_in[0];
    const int*   tags      = (const int*)d_in[1];
    const float* mask      = (const float*)d_in[2];
    const float* trans     = (const float*)d_in[3];
    float* out = (float*)d_out;

    hipMemsetAsync(out, 0, sizeof(float), stream);
    crf_nll_kernel<<<dim3(BB), dim3(64), 0, stream>>>(emissions, tags, mask, trans, out);
}